// Round 2
// baseline (1027.002 us; speedup 1.0000x reference)
//
#include <hip/hip_runtime.h>
#include <hip/hip_bf16.h>

#define B_ 128
#define S_ 512
#define H_ 1024
#define E_ 1024
#define V_ 50000
#define EXTRA_ 500
#define VE_ 50500
#define EPS_ 1e-8f

typedef __attribute__((ext_vector_type(4))) float f32x4;
typedef __attribute__((ext_vector_type(8))) short bf16x8;

__device__ __forceinline__ unsigned short f2bf(float f) {
    unsigned u = __builtin_bit_cast(unsigned, f);
    u = (u + 0x7FFFu + ((u >> 16) & 1u)) >> 16;
    return (unsigned short)u;
}

__device__ __forceinline__ bf16x8 pack8(const float* f) {
    union { bf16x8 v; unsigned short s[8]; } u;
#pragma unroll
    for (int i = 0; i < 8; ++i) u.s[i] = f2bf(f[i]);
    return u.v;
}

__device__ __forceinline__ float fast_tanh(float x) {
    x = fminf(fmaxf(x, -15.f), 15.f);
    float e = __expf(2.f * x);
    return __fdividef(e - 1.f, e + 1.f);
}

// ---------------- K1: embedding + layernorm + concat ----------------
__global__ __launch_bounds__(256) void embed_ln_kernel(
    const int* __restrict__ tok, const float* __restrict__ embed,
    const float* __restrict__ g, const float* __restrict__ beta,
    const float* __restrict__ ctx, float* __restrict__ x_cat)
{
    __shared__ float red[256];
    int b = blockIdx.x, t = threadIdx.x;
    const float* row = embed + (size_t)tok[b] * E_;
    float v[4];
    float s = 0.f;
#pragma unroll
    for (int i = 0; i < 4; ++i) { v[i] = row[t + i*256]; s += v[i]; }
    red[t] = s; __syncthreads();
    for (int o = 128; o > 0; o >>= 1) { if (t < o) red[t] += red[t+o]; __syncthreads(); }
    float mu = red[0] * (1.f/E_);
    __syncthreads();
    s = 0.f;
#pragma unroll
    for (int i = 0; i < 4; ++i) { float d = v[i]-mu; s += d*d; }
    red[t] = s; __syncthreads();
    for (int o = 128; o > 0; o >>= 1) { if (t < o) red[t] += red[t+o]; __syncthreads(); }
    float inv = rsqrtf(red[0]*(1.f/E_) + 1e-5f);
    float* xrow = x_cat + (size_t)b * 2048;
#pragma unroll
    for (int i = 0; i < 4; ++i) {
        int j = t + i*256;
        xrow[j] = (v[i]-mu)*inv*g[j] + beta[j];
        xrow[1024 + j] = ctx[b*1024 + j];
    }
}

// ---------------- generic M=128 GEMM: C[128,ldc] = A[128,K] @ W[N,K]^T + bias ----------------
__global__ __launch_bounds__(256) void gemm128_kernel(
    const float* __restrict__ A, const float* __restrict__ W,
    const float* __restrict__ bias, float* __restrict__ C,
    int N, int K, int ldc)
{
    __shared__ char Ab[128*64*2];
    __shared__ char Wb[64*64*2];
    const int t = threadIdx.x;
    const int wid = t >> 6, lane = t & 63;
    const int waveM = wid >> 1, waveN = wid & 1;
    const int lq = lane >> 4, lr = lane & 15;
    const int n0 = blockIdx.x * 64;
    f32x4 acc[4][2];
#pragma unroll
    for (int i = 0; i < 4; ++i)
#pragma unroll
        for (int j = 0; j < 2; ++j) acc[i][j] = (f32x4){0.f,0.f,0.f,0.f};
    for (int kc = 0; kc < K; kc += 64) {
        __syncthreads();
#pragma unroll
        for (int i = 0; i < 4; ++i) {       // stage A chunk [128][64]
            int c = t + i*256;
            int row = c >> 3, k8 = (c & 7) << 3;
            const float* src = A + (size_t)row*K + kc + k8;
            float f[8];
            *(float4*)f     = *(const float4*)src;
            *(float4*)(f+4) = *(const float4*)(src+4);
            int byte = row*128 + ((k8*2) ^ ((row&7)<<4));
            *(bf16x8*)(Ab + byte) = pack8(f);
        }
#pragma unroll
        for (int i = 0; i < 2; ++i) {       // stage W chunk [64][64]
            int c = t + i*256;
            int row = c >> 3, k8 = (c & 7) << 3;
            int n = n0 + row;
            float f[8] = {0,0,0,0,0,0,0,0};
            if (n < N) {
                const float* src = W + (size_t)n*K + kc + k8;
                *(float4*)f     = *(const float4*)src;
                *(float4*)(f+4) = *(const float4*)(src+4);
            }
            int byte = row*128 + ((k8*2) ^ ((row&7)<<4));
            *(bf16x8*)(Wb + byte) = pack8(f);
        }
        __syncthreads();
#pragma unroll
        for (int kf = 0; kf < 2; ++kf) {
            int kk2 = (kf*32 + (lq<<3)) * 2;
            bf16x8 bfr[2];
#pragma unroll
            for (int nf = 0; nf < 2; ++nf) {
                int r = waveN*32 + nf*16 + lr;
                bfr[nf] = *(const bf16x8*)(Wb + r*128 + (kk2 ^ ((r&7)<<4)));
            }
#pragma unroll
            for (int mf = 0; mf < 4; ++mf) {
                int r = waveM*64 + mf*16 + lr;
                bf16x8 afr = *(const bf16x8*)(Ab + r*128 + (kk2 ^ ((r&7)<<4)));
#pragma unroll
                for (int nf = 0; nf < 2; ++nf)
                    acc[mf][nf] = __builtin_amdgcn_mfma_f32_16x16x32_bf16(afr, bfr[nf], acc[mf][nf], 0, 0, 0);
            }
        }
    }
#pragma unroll
    for (int mf = 0; mf < 4; ++mf)
#pragma unroll
        for (int nf = 0; nf < 2; ++nf) {
            int n = n0 + waveN*32 + nf*16 + lr;
            if (n < N) {
                float bv = bias[n];
#pragma unroll
                for (int r = 0; r < 4; ++r) {
                    int m = waveM*64 + mf*16 + (lq<<2) + r;
                    C[(size_t)m*ldc + n] = acc[mf][nf][r] + bv;
                }
            }
        }
}

// ---------------- K4: GRU gates ----------------
__global__ __launch_bounds__(256) void gru_gate_kernel(
    const float* __restrict__ gx, const float* __restrict__ gh,
    const float* __restrict__ h0, float* __restrict__ s_t)
{
    int i = blockIdx.x*256 + threadIdx.x;
    int b = i >> 10, h = i & 1023;
    const float* gxr = gx + (size_t)b*3072;
    const float* ghr = gh + (size_t)b*3072;
    float r = 1.f/(1.f+expf(-(gxr[h]      + ghr[h])));
    float z = 1.f/(1.f+expf(-(gxr[h+1024] + ghr[h+1024])));
    float n = tanhf(gxr[h+2048] + r*ghr[h+2048]);
    s_t[i] = (1.f-z)*n + z*h0[i];
}

// ---------------- K6: fused attention-score GEMM ----------------
// BM=128, BN=256, BK=64; 8 waves (2M x 4N); grid 512*4=2048
// e_part[nt][65536] = sum_n tanh(enc@Wh^T + dec_feat + cov*Wc) * Vv over this n-tile
__global__ __launch_bounds__(512,4) void attn_gemm_kernel(
    const float* __restrict__ enc, const float* __restrict__ Wh,
    const float* __restrict__ dec_feat, const float* __restrict__ coverage,
    const float* __restrict__ Wc, const float* __restrict__ Vv,
    float* __restrict__ e_part)
{
    __shared__ char Ab[128*64*2];      // 16 KB
    __shared__ char Bb[256*64*2];      // 32 KB
    __shared__ float e_lds[4][128];
    const int t = threadIdx.x;
    const int wid = t >> 6, lane = t & 63;
    const int waveM = wid >> 2, waveN = wid & 3;
    const int lq = lane >> 4, lr = lane & 15;
    // XCD-chunked bijective swizzle (2048 % 8 == 0): each XCD gets 256 logical ids
    int bid = blockIdx.x;
    int wg = (bid & 7) * 256 + (bid >> 3);
    const int mt = wg >> 2, nt = wg & 3;
    const int m0 = mt * 128, n0 = nt * 256;
    const int b = m0 >> 9;

    const int arow = t >> 2, ak0 = (t & 3) * 16;   // A stage: 4 thr/row, 16 f32 each
    const int brow = t >> 1, bk0 = (t & 1) * 32;   // B stage: 2 thr/row, 32 f32 each

    f32x4 acc[4][4];
#pragma unroll
    for (int i = 0; i < 4; ++i)
#pragma unroll
        for (int j = 0; j < 4; ++j) acc[i][j] = (f32x4){0.f,0.f,0.f,0.f};

    for (int kc = 0; kc < 1024; kc += 64) {
        __syncthreads();
        {   // stage A [128][64] f32 -> bf16 (XOR-swizzled)
            const float* src = enc + (size_t)(m0 + arow)*H_ + kc + ak0;
            float f[16];
            *(float4*)(f)    = *(const float4*)(src);
            *(float4*)(f+4)  = *(const float4*)(src+4);
            *(float4*)(f+8)  = *(const float4*)(src+8);
            *(float4*)(f+12) = *(const float4*)(src+12);
            char* dst = Ab + arow*128;
            int sw = (arow & 7) << 4;
            *(bf16x8*)(dst + ((ak0*2)      ^ sw)) = pack8(f);
            *(bf16x8*)(dst + ((ak0*2 + 16) ^ sw)) = pack8(f+8);
        }
        {   // stage B [256][64]
            const float* src = Wh + (size_t)(n0 + brow)*H_ + kc + bk0;
            char* dst = Bb + brow*128;
            int sw = (brow & 7) << 4;
            float f[16];
            *(float4*)(f)    = *(const float4*)(src);
            *(float4*)(f+4)  = *(const float4*)(src+4);
            *(float4*)(f+8)  = *(const float4*)(src+8);
            *(float4*)(f+12) = *(const float4*)(src+12);
            *(bf16x8*)(dst + ((bk0*2)      ^ sw)) = pack8(f);
            *(bf16x8*)(dst + ((bk0*2 + 16) ^ sw)) = pack8(f+8);
            *(float4*)(f)    = *(const float4*)(src+16);
            *(float4*)(f+4)  = *(const float4*)(src+20);
            *(float4*)(f+8)  = *(const float4*)(src+24);
            *(float4*)(f+12) = *(const float4*)(src+28);
            *(bf16x8*)(dst + ((bk0*2 + 32) ^ sw)) = pack8(f);
            *(bf16x8*)(dst + ((bk0*2 + 48) ^ sw)) = pack8(f+8);
        }
        __syncthreads();
#pragma unroll
        for (int kf = 0; kf < 2; ++kf) {
            const int koff = kf*64 + lq*16;
            bf16x8 bfr[4];
#pragma unroll
            for (int nf = 0; nf < 4; ++nf) {
                int r = waveN*64 + nf*16 + lr;
                bfr[nf] = *(const bf16x8*)(Bb + r*128 + (koff ^ ((r&7)<<4)));
            }
#pragma unroll
            for (int mf = 0; mf < 4; ++mf) {
                int r = waveM*64 + mf*16 + lr;
                bf16x8 afr = *(const bf16x8*)(Ab + r*128 + (koff ^ ((r&7)<<4)));
#pragma unroll
                for (int nf = 0; nf < 4; ++nf)
                    acc[mf][nf] = __builtin_amdgcn_mfma_f32_16x16x32_bf16(afr, bfr[nf], acc[mf][nf], 0, 0, 0);
            }
        }
    }
    // epilogue: tanh + Vv partial reduce
    float cv[4][4];
#pragma unroll
    for (int mf = 0; mf < 4; ++mf)
#pragma unroll
        for (int r = 0; r < 4; ++r) {
            int m = m0 + waveM*64 + mf*16 + lq*4 + r;
            cv[mf][r] = coverage[b*S_ + (m & 511)];
        }
    float e_acc[4][4] = {};
#pragma unroll
    for (int nf = 0; nf < 4; ++nf) {
        int n = n0 + waveN*64 + nf*16 + lr;
        float df = dec_feat[b*H_ + n];
        float wc = Wc[n];
        float vv = Vv[n];
#pragma unroll
        for (int mf = 0; mf < 4; ++mf)
#pragma unroll
            for (int r = 0; r < 4; ++r)
                e_acc[mf][r] += fast_tanh(acc[mf][nf][r] + df + cv[mf][r]*wc) * vv;
    }
#pragma unroll
    for (int msk = 1; msk < 16; msk <<= 1)
#pragma unroll
        for (int mf = 0; mf < 4; ++mf)
#pragma unroll
            for (int r = 0; r < 4; ++r)
                e_acc[mf][r] += __shfl_xor(e_acc[mf][r], msk);
    if (lr == 0) {
#pragma unroll
        for (int mf = 0; mf < 4; ++mf)
#pragma unroll
            for (int r = 0; r < 4; ++r)
                e_lds[waveN][waveM*64 + mf*16 + lq*4 + r] = e_acc[mf][r];
    }
    __syncthreads();
    if (t < 128)
        e_part[(size_t)nt*65536 + m0 + t] = e_lds[0][t] + e_lds[1][t] + e_lds[2][t] + e_lds[3][t];
}

// ---------------- K7: softmax over S + coverage ----------------
__global__ __launch_bounds__(256) void attn_softmax_kernel(
    const float* __restrict__ e_part, const float* __restrict__ mask,
    const float* __restrict__ cov, float* __restrict__ att,
    float* __restrict__ cov_next, float* __restrict__ loss)
{
    __shared__ float red[256];
    int b = blockIdx.x, t = threadIdx.x;
    int i1 = b*S_ + t, i2 = i1 + 256;
    float e1 = e_part[i1] + e_part[65536+i1] + e_part[131072+i1] + e_part[196608+i1] + mask[i1];
    float e2 = e_part[i2] + e_part[65536+i2] + e_part[131072+i2] + e_part[196608+i2] + mask[i2];
    red[t] = fmaxf(e1, e2); __syncthreads();
    for (int o = 128; o > 0; o >>= 1) { if (t < o) red[t] = fmaxf(red[t], red[t+o]); __syncthreads(); }
    float m = red[0]; __syncthreads();
    float a1 = expf(e1-m), a2 = expf(e2-m);
    red[t] = a1+a2; __syncthreads();
    for (int o = 128; o > 0; o >>= 1) { if (t < o) red[t] += red[t+o]; __syncthreads(); }
    float inv = 1.f/red[0]; __syncthreads();
    a1 *= inv; a2 *= inv;
    att[i1] = a1; att[i2] = a2;
    float c1 = cov[i1]+a1, c2 = cov[i2]+a2;
    cov_next[i1] = c1; cov_next[i2] = c2;
    red[t] = fminf(a1,c1)+fminf(a2,c2); __syncthreads();
    for (int o = 128; o > 0; o >>= 1) { if (t < o) red[t] += red[t+o]; __syncthreads(); }
    if (t == 0) loss[b] = red[0];
}

// ---------------- K8: h_t = att @ enc, s-split into 4 partials ----------------
__global__ __launch_bounds__(256) void context_part_kernel(
    const float* __restrict__ att, const float* __restrict__ enc, float* __restrict__ hq)
{
    __shared__ float asl[128];
    int b = blockIdx.x, sub = blockIdx.y;
    int hh = sub & 1, q = sub >> 1;
    int t = threadIdx.x;
    if (t < 128) asl[t] = att[b*S_ + q*128 + t];
    __syncthreads();
    int h = hh*512 + t*2;
    const float* ep = enc + (size_t)b*S_*H_ + (size_t)q*128*H_ + h;
    float a0 = 0.f, a1 = 0.f;
#pragma unroll 4
    for (int s = 0; s < 128; ++s) {
        float2 v = *(const float2*)(ep + (size_t)s*H_);
        float w = asl[s];
        a0 += w*v.x; a1 += w*v.y;
    }
    float* o = hq + ((size_t)q*B_ + b)*H_ + h;
    o[0] = a0; o[1] = a1;
}

__global__ __launch_bounds__(256) void context_reduce_kernel(
    const float* __restrict__ hq, float* __restrict__ h_t)
{
    int i = blockIdx.x*256 + threadIdx.x;  // 131072
    h_t[i] = hq[i] + hq[131072+i] + hq[262144+i] + hq[393216+i];
}

// ---------------- K9: p_gen + build A2=[s_t,h_t] ----------------
__global__ __launch_bounds__(256) void pgen_kernel(
    const float* __restrict__ h_t, const float* __restrict__ s_t, const float* __restrict__ x,
    const float* __restrict__ pgW, const float* __restrict__ pgb,
    float* __restrict__ pgen, float* __restrict__ A2)
{
    __shared__ float red[256];
    int b = blockIdx.x, t = threadIdx.x;
    float s = 0.f;
#pragma unroll
    for (int i = 0; i < 12; ++i) {
        int j = t + i*256;
        float v = (j < 1024) ? h_t[b*1024+j] : (j < 2048 ? s_t[b*1024 + j-1024] : x[b*1024 + j-2048]);
        s += v * pgW[j];
    }
    red[t] = s; __syncthreads();
    for (int o = 128; o > 0; o >>= 1) { if (t < o) red[t] += red[t+o]; __syncthreads(); }
    if (t == 0) {
        float p = 1.f/(1.f+expf(-(red[0] + pgb[0])));
        pgen[b] = fmaxf(p, EPS_);
    }
#pragma unroll
    for (int i = 0; i < 8; ++i) {
        int j = t + i*256;
        A2[(size_t)b*2048 + j] = (j < 1024) ? s_t[b*1024+j] : h_t[b*1024+j-1024];
    }
}

// ---------------- K11: logits = h2 @ out2_W^T + b ----------------
// A[128][1024] in registers (wave w holds rows 16w..16w+15); W streamed through
// double-buffered LDS in 16-row chunks. grid 256 x 512 thr. grid-stride over 3125 chunks.
__global__ __launch_bounds__(512,4) void logits_kernel(
    const float* __restrict__ A, const float* __restrict__ W,
    const float* __restrict__ bias, float* __restrict__ C)
{
    __shared__ char Wb[2][16*1024*2];   // 2 x 32 KB
    const int t = threadIdx.x, wid = t >> 6, lane = t & 63;
    const int lq = lane >> 4, lr = lane & 15;
    bf16x8 a[32];
    {
        const float* ar = A + (size_t)(wid*16 + lr)*1024 + lq*8;
#pragma unroll
        for (int kf = 0; kf < 32; ++kf) {
            float f[8];
            *(float4*)f     = *(const float4*)(ar + kf*32);
            *(float4*)(f+4) = *(const float4*)(ar + kf*32 + 4);
            a[kf] = pack8(f);
        }
    }
    const int srow = t >> 5, sk0 = (t & 31) * 32;
    const int NCH = V_ / 16;    // 3125
    int c = blockIdx.x;
    float wreg[32];
    {
        const float* src = W + (size_t)(c*16 + srow)*1024 + sk0;
#pragma unroll
        for (int j = 0; j < 8; ++j) *(float4*)(wreg + j*4) = *(const float4*)(src + j*4);
    }
    int cur = 0;
    const int swc = (srow & 7) << 4;
    const int swr = (lr & 7) << 4;
    while (true) {
        {
            char* dst = Wb[cur] + srow*2048;
#pragma unroll
            for (int j = 0; j < 4; ++j)
                *(bf16x8*)(dst + (((sk0 + j*8)*2) ^ swc)) = pack8(wreg + j*8);
        }
        __syncthreads();
        int cn = c + 256;
        if (cn < NCH) {
            const float* src = W + (size_t)(cn*16 + srow)*1024 + sk0;
#pragma unroll
            for (int j = 0; j < 8; ++j) *(float4*)(wreg + j*4) = *(const float4*)(src + j*4);
        }
        f32x4 acc = (f32x4){0.f,0.f,0.f,0.f};
        const char* wb = Wb[cur] + lr*2048;
#pragma unroll
        for (int kf = 0; kf < 32; ++kf) {
            bf16x8 bfr = *(const bf16x8*)(wb + ((kf*64 + lq*16) ^ swr));
            acc = __builtin_amdgcn_mfma_f32_16x16x32_bf16(a[kf], bfr, acc, 0, 0, 0);
        }
        int n = c*16 + lr;
        float bv = bias[n];
        float* cp = C + (size_t)(wid*16 + lq*4)*VE_ + n;
#pragma unroll
        for (int r = 0; r < 4; ++r) cp[(size_t)r*VE_] = acc[r] + bv;
        c = cn;
        if (c >= NCH) break;
        cur ^= 1;
    }
}

// ---------------- K12: vocab softmax in place ----------------
__global__ __launch_bounds__(1024) void vocab_softmax_kernel(
    float* __restrict__ out0, const float* __restrict__ pgen)
{
    __shared__ float rm[1024], rl[1024];
    int b = blockIdx.x, t = threadIdx.x;
    float* row = out0 + (size_t)b*VE_;
    float m = -1e30f, l = 0.f;
    for (int i = t; i < V_; i += 1024) {
        float xv = row[i];
        if (xv > m) { l = l*__expf(m-xv) + 1.f; m = xv; }
        else l += __expf(xv-m);
    }
    rm[t] = m; rl[t] = l; __syncthreads();
    for (int o = 512; o > 0; o >>= 1) {
        if (t < o) {
            float m1 = rm[t], m2 = rm[t+o];
            float M = fmaxf(m1, m2);
            rl[t] = rl[t]*__expf(m1-M) + rl[t+o]*__expf(m2-M);
            rm[t] = M;
        }
        __syncthreads();
    }
    float M = rm[0], inv = pgen[b]/rl[0];
    for (int i = t; i < V_; i += 1024)
        row[i] = __expf(row[i]-M)*inv;
    for (int i = V_ + t; i < VE_; i += 1024)
        row[i] = 0.f;
}

// ---------------- K13: scatter-add copy distribution ----------------
__global__ __launch_bounds__(256) void scatter_kernel(
    const int* __restrict__ ebev, const float* __restrict__ att,
    const float* __restrict__ pgen, float* __restrict__ out0)
{
    int i = blockIdx.x*256 + threadIdx.x;
    int b = i >> 9;
    float val = (1.f - pgen[b]) * att[i];
    int col = ebev[i];
    atomicAdd(out0 + (size_t)b*VE_ + col, val);
}

// ---------------- K14: clip + log in place ----------------
__global__ __launch_bounds__(256) void log_kernel(float* __restrict__ out0)
{
    int i = (blockIdx.x*256 + threadIdx.x) * 4;
    if (i >= B_*VE_) return;
    float4 v = *(float4*)(out0 + i);
    v.x = logf(fmaxf(v.x, EPS_));
    v.y = logf(fmaxf(v.y, EPS_));
    v.z = logf(fmaxf(v.z, EPS_));
    v.w = logf(fmaxf(v.w, EPS_));
    *(float4*)(out0 + i) = v;
}

extern "C" void kernel_launch(void* const* d_in, const int* in_sizes, int n_in,
                              void* d_out, int out_size, void* d_ws, size_t ws_size,
                              hipStream_t stream) {
    const int*   tok        = (const int*)d_in[0];
    const float* dec_hidden = (const float*)d_in[1];
    const float* enc        = (const float*)d_in[2];
    const float* mask       = (const float*)d_in[3];
    const float* ctx1       = (const float*)d_in[4];
    const int*   ebev       = (const int*)d_in[5];
    const float* cov        = (const float*)d_in[7];
    const float* embed      = (const float*)d_in[8];
    const float* ln_g       = (const float*)d_in[9];
    const float* ln_b       = (const float*)d_in[10];
    const float* xc_W       = (const float*)d_in[11];
    const float* xc_b       = (const float*)d_in[12];
    const float* W_ih       = (const float*)d_in[13];
    const float* W_hh       = (const float*)d_in[14];
    const float* b_ih       = (const float*)d_in[15];
    const float* b_hh       = (const float*)d_in[16];
    const float* Wh         = (const float*)d_in[17];
    const float* Ws         = (const float*)d_in[18];
    const float* Ws_b       = (const float*)d_in[19];
    const float* Wc         = (const float*)d_in[20];
    const float* Vv         = (const float*)d_in[21];
    const float* pg_W       = (const float*)d_in[22];
    const float* pg_b       = (const float*)d_in[23];
    const float* out1_W     = (const float*)d_in[24];
    const float* out1_b     = (const float*)d_in[25];
    const float* out2_W     = (const float*)d_in[26];
    const float* out2_b     = (const float*)d_in[27];

    float* out      = (float*)d_out;
    float* s_t      = out + 6464000;   // [B,H]
    float* h_t      = out + 6595072;   // [B,H]
    float* cov_next = out + 6726144;   // [B,S]
    float* loss     = out + 6791680;   // [B]

    float* wsf = (float*)d_ws;
    float* x_cat    = wsf;             // [B,2048]
    float* x        = wsf + 262144;    // [B,1024]
    float* gx       = wsf + 393216;    // [B,3072]
    float* gh       = wsf + 786432;    // [B,3072]
    float* dec_feat = wsf + 1179648;   // [B,1024]
    float* e_part   = wsf + 1310720;   // [4][65536]
    float* att      = wsf + 1572864;   // [B,S]
    float* pgen     = wsf + 1638400;   // [B]
    float* A2       = wsf + 1638528;   // [B,2048]
    float* h2       = wsf + 1900672;   // [B,1024]
    float* hq       = wsf + 2031744;   // [4][B,1024]

    embed_ln_kernel<<<128, 256, 0, stream>>>(tok, embed, ln_g, ln_b, ctx1, x_cat);
    gemm128_kernel<<<16, 256, 0, stream>>>(x_cat, xc_W, xc_b, x, 1024, 2048, 1024);
    gemm128_kernel<<<48, 256, 0, stream>>>(x, W_ih, b_ih, gx, 3072, 1024, 3072);
    gemm128_kernel<<<48, 256, 0, stream>>>(dec_hidden, W_hh, b_hh, gh, 3072, 1024, 3072);
    gru_gate_kernel<<<512, 256, 0, stream>>>(gx, gh, dec_hidden, s_t);
    gemm128_kernel<<<16, 256, 0, stream>>>(s_t, Ws, Ws_b, dec_feat, 1024, 1024, 1024);
    attn_gemm_kernel<<<2048, 512, 0, stream>>>(enc, Wh, dec_feat, cov, Wc, Vv, e_part);
    attn_softmax_kernel<<<128, 256, 0, stream>>>(e_part, mask, cov, att, cov_next, loss);
    dim3 g8(128, 8);
    context_part_kernel<<<g8, 256, 0, stream>>>(att, enc, hq);
    context_reduce_kernel<<<512, 256, 0, stream>>>(hq, h_t);
    pgen_kernel<<<128, 256, 0, stream>>>(h_t, s_t, x, pg_W, pg_b, pgen, A2);
    gemm128_kernel<<<16, 256, 0, stream>>>(A2, out1_W, out1_b, h2, 1024, 2048, 1024);
    logits_kernel<<<256, 512, 0, stream>>>(h2, out2_W, out2_b, out);
    vocab_softmax_kernel<<<128, 1024, 0, stream>>>(out, pgen);
    scatter_kernel<<<256, 256, 0, stream>>>(ebev, att, pgen, out);
    log_kernel<<<6313, 256, 0, stream>>>(out);
}

// Round 4
// 547.675 us; speedup vs baseline: 1.8752x; 1.8752x over previous
//
#include <hip/hip_runtime.h>
#include <hip/hip_bf16.h>
#include <stdint.h>

#define B_ 128
#define S_ 512
#define H_ 1024
#define E_ 1024
#define V_ 50000
#define EXTRA_ 500
#define VE_ 50500
#define EPS_ 1e-8f

typedef __attribute__((ext_vector_type(4))) float f32x4;
typedef __attribute__((ext_vector_type(8))) short bf16x8;

__device__ __forceinline__ unsigned short f2bf(float f) {
    unsigned u = __builtin_bit_cast(unsigned, f);
    u = (u + 0x7FFFu + ((u >> 16) & 1u)) >> 16;
    return (unsigned short)u;
}

__device__ __forceinline__ bf16x8 pack8(const float* f) {
    union { bf16x8 v; unsigned short s[8]; } u;
#pragma unroll
    for (int i = 0; i < 8; ++i) u.s[i] = f2bf(f[i]);
    return u.v;
}

__device__ __forceinline__ float bf2f(unsigned short s) {
    unsigned u = (unsigned)s << 16;
    return __builtin_bit_cast(float, u);
}

__device__ __forceinline__ float fast_tanh(float x) {
    x = fminf(fmaxf(x, -15.f), 15.f);
    float e = __expf(2.f * x);
    return __fdividef(e - 1.f, e + 1.f);
}

// async global->LDS, 16 bytes per lane; lds dest must be wave-uniform-base + lane*16
__device__ __forceinline__ void gload16(const void* g, void* l) {
    __builtin_amdgcn_global_load_lds(
        reinterpret_cast<const __attribute__((address_space(1))) unsigned int*>(
            reinterpret_cast<uintptr_t>(g)),
        reinterpret_cast<__attribute__((address_space(3))) unsigned int*>(
            reinterpret_cast<uintptr_t>(l)),
        16, 0, 0);
}

// ---------------- K0: f32 -> bf16 convert ----------------
__global__ __launch_bounds__(256) void cvt_bf16_kernel(const float* __restrict__ in,
                                                       unsigned short* __restrict__ out) {
    int i = (blockIdx.x * 256 + threadIdx.x) * 8;
    float f[8];
    *(float4*)f     = *(const float4*)(in + i);
    *(float4*)(f+4) = *(const float4*)(in + i + 4);
    union { uint4 v; unsigned short s[8]; } u;
#pragma unroll
    for (int j = 0; j < 8; ++j) u.s[j] = f2bf(f[j]);
    *(uint4*)(out + i) = u.v;
}

// ---------------- K1: embedding + layernorm + concat ----------------
__global__ __launch_bounds__(256) void embed_ln_kernel(
    const int* __restrict__ tok, const float* __restrict__ embed,
    const float* __restrict__ g, const float* __restrict__ beta,
    const float* __restrict__ ctx, float* __restrict__ x_cat)
{
    __shared__ float red[256];
    int b = blockIdx.x, t = threadIdx.x;
    const float* row = embed + (size_t)tok[b] * E_;
    float v[4];
    float s = 0.f;
#pragma unroll
    for (int i = 0; i < 4; ++i) { v[i] = row[t + i*256]; s += v[i]; }
    red[t] = s; __syncthreads();
    for (int o = 128; o > 0; o >>= 1) { if (t < o) red[t] += red[t+o]; __syncthreads(); }
    float mu = red[0] * (1.f/E_);
    __syncthreads();
    s = 0.f;
#pragma unroll
    for (int i = 0; i < 4; ++i) { float d = v[i]-mu; s += d*d; }
    red[t] = s; __syncthreads();
    for (int o = 128; o > 0; o >>= 1) { if (t < o) red[t] += red[t+o]; __syncthreads(); }
    float inv = rsqrtf(red[0]*(1.f/E_) + 1e-5f);
    float* xrow = x_cat + (size_t)b * 2048;
#pragma unroll
    for (int i = 0; i < 4; ++i) {
        int j = t + i*256;
        xrow[j] = (v[i]-mu)*inv*g[j] + beta[j];
        xrow[1024 + j] = ctx[b*1024 + j];
    }
}

// ---------------- generic M=128 GEMM with optional K-split ----------------
// C_part[blockIdx.y][128][ldc] = A[128, kchunk slice] @ W[N, slice]^T (+bias on slice 0)
__global__ __launch_bounds__(256) void gemm128_kernel(
    const float* __restrict__ A, const float* __restrict__ W,
    const float* __restrict__ bias, float* __restrict__ C,
    int N, int K, int ldc, int kchunk)
{
    __shared__ char Ab[128*64*2];
    __shared__ char Wb[64*64*2];
    const int t = threadIdx.x;
    const int wid = t >> 6, lane = t & 63;
    const int waveM = wid >> 1, waveN = wid & 1;
    const int lq = lane >> 4, lr = lane & 15;
    const int n0 = blockIdx.x * 64;
    const int kbeg = blockIdx.y * kchunk, kend = kbeg + kchunk;
    f32x4 acc[4][2];
#pragma unroll
    for (int i = 0; i < 4; ++i)
#pragma unroll
        for (int j = 0; j < 2; ++j) acc[i][j] = (f32x4){0.f,0.f,0.f,0.f};
    for (int kc = kbeg; kc < kend; kc += 64) {
        __syncthreads();
#pragma unroll
        for (int i = 0; i < 4; ++i) {
            int c = t + i*256;
            int row = c >> 3, k8 = (c & 7) << 3;
            const float* src = A + (size_t)row*K + kc + k8;
            float f[8];
            *(float4*)f     = *(const float4*)src;
            *(float4*)(f+4) = *(const float4*)(src+4);
            int byte = row*128 + ((k8*2) ^ ((row&7)<<4));
            *(bf16x8*)(Ab + byte) = pack8(f);
        }
#pragma unroll
        for (int i = 0; i < 2; ++i) {
            int c = t + i*256;
            int row = c >> 3, k8 = (c & 7) << 3;
            int n = n0 + row;
            float f[8] = {0,0,0,0,0,0,0,0};
            if (n < N) {
                const float* src = W + (size_t)n*K + kc + k8;
                *(float4*)f     = *(const float4*)src;
                *(float4*)(f+4) = *(const float4*)(src+4);
            }
            int byte = row*128 + ((k8*2) ^ ((row&7)<<4));
            *(bf16x8*)(Wb + byte) = pack8(f);
        }
        __syncthreads();
#pragma unroll
        for (int kf = 0; kf < 2; ++kf) {
            int kk2 = (kf*32 + (lq<<3)) * 2;
            bf16x8 bfr[2];
#pragma unroll
            for (int nf = 0; nf < 2; ++nf) {
                int r = waveN*32 + nf*16 + lr;
                bfr[nf] = *(const bf16x8*)(Wb + r*128 + (kk2 ^ ((r&7)<<4)));
            }
#pragma unroll
            for (int mf = 0; mf < 4; ++mf) {
                int r = waveM*64 + mf*16 + lr;
                bf16x8 afr = *(const bf16x8*)(Ab + r*128 + (kk2 ^ ((r&7)<<4)));
#pragma unroll
                for (int nf = 0; nf < 2; ++nf)
                    acc[mf][nf] = __builtin_amdgcn_mfma_f32_16x16x32_bf16(afr, bfr[nf], acc[mf][nf], 0, 0, 0);
            }
        }
    }
    float* Cp = C + (size_t)blockIdx.y * 128 * (size_t)ldc;
    bool addb = (bias != nullptr) && (blockIdx.y == 0);
#pragma unroll
    for (int mf = 0; mf < 4; ++mf)
#pragma unroll
        for (int nf = 0; nf < 2; ++nf) {
            int n = n0 + waveN*32 + nf*16 + lr;
            if (n < N) {
                float bv = addb ? bias[n] : 0.f;
#pragma unroll
                for (int r = 0; r < 4; ++r) {
                    int m = waveM*64 + mf*16 + (lq<<2) + r;
                    Cp[(size_t)m*ldc + n] = acc[mf][nf][r] + bv;
                }
            }
        }
}

// ---------------- reduce 4 partial slices ----------------
__global__ __launch_bounds__(256) void reduce4_kernel(
    const float* __restrict__ in, float* __restrict__ out, int len)
{
    int i = blockIdx.x*256 + threadIdx.x;
    if (i < len) out[i] = in[i] + in[len+i] + in[2*len+i] + in[3*len+i];
}

// ---------------- GRU gates (reads 2-way K-split partials) ----------------
__global__ __launch_bounds__(256) void gru_gate_kernel(
    const float* __restrict__ gxp, const float* __restrict__ ghp,
    const float* __restrict__ h0, float* __restrict__ s_t)
{
    int i = blockIdx.x*256 + threadIdx.x;
    int b = i >> 10, h = i & 1023;
    const float* gx0 = gxp + (size_t)b*3072;
    const float* gx1 = gx0 + 393216;
    const float* gh0 = ghp + (size_t)b*3072;
    const float* gh1 = gh0 + 393216;
    float grx = gx0[h] + gx1[h],        grh = gh0[h] + gh1[h];
    float gzx = gx0[h+1024]+gx1[h+1024], gzh = gh0[h+1024]+gh1[h+1024];
    float gnx = gx0[h+2048]+gx1[h+2048], gnh = gh0[h+2048]+gh1[h+2048];
    float r = 1.f/(1.f+__expf(-(grx + grh)));
    float z = 1.f/(1.f+__expf(-(gzx + gzh)));
    float n = fast_tanh(gnx + r*gnh);
    s_t[i] = (1.f-z)*n + z*h0[i];
}

// ---------------- K6 (bf16): fused attention-score GEMM, m97 structure ----------------
// BM=128,BN=128,BK=64; 4 waves (2x2); grid 512*8=4096, global_load_lds staging
__global__ __launch_bounds__(256,3) void attn_gemm_bf16_kernel(
    const unsigned short* __restrict__ encb,   // [65536,1024] bf16
    const unsigned short* __restrict__ whb,    // [1024,1024] bf16
    const float* __restrict__ dec_feat, const float* __restrict__ coverage,
    const float* __restrict__ Wc, const float* __restrict__ Vv,
    float* __restrict__ e_part)                // [8][65536]
{
    __shared__ char Ab[128*128];   // [128 rows][64 bf16] linear
    __shared__ char Bb[128*128];
    __shared__ float e_lds[2][128];
    const int t = threadIdx.x;
    const int wid = t >> 6, lane = t & 63;
    const int waveM = wid >> 1, waveN = wid & 1;
    const int lq = lane >> 4, lr = lane & 15;
    // XCD-chunked bijective swizzle; nt fast so 8 n-tiles of an m-panel co-run on one XCD
    int bid = blockIdx.x;
    int wg = (bid & 7) * 512 + (bid >> 3);
    const int nt = wg & 7, mt = wg >> 3;
    const int m0 = mt * 128, n0 = nt * 128;
    const int b = m0 >> 9;

    const int grow = wid*8 + (lane >> 3);      // staging row within 32-row group
    const int gk16 = lane & 7;                 // 16B unit within 128B row
    const unsigned short* asrc = encb + (size_t)(m0 + grow)*H_ + gk16*8;
    const unsigned short* bsrc = whb  + (size_t)(n0 + grow)*H_ + gk16*8;
    char* aldst = Ab + wid*1024;
    char* bldst = Bb + wid*1024;

    f32x4 acc[4][4];
#pragma unroll
    for (int i = 0; i < 4; ++i)
#pragma unroll
        for (int j = 0; j < 4; ++j) acc[i][j] = (f32x4){0.f,0.f,0.f,0.f};

    for (int kc = 0; kc < 1024; kc += 64) {
        __syncthreads();
#pragma unroll
        for (int i = 0; i < 4; ++i) {
            gload16(asrc + kc + i*32*H_, aldst + i*4096);
            gload16(bsrc + kc + i*32*H_, bldst + i*4096);
        }
        __syncthreads();
#pragma unroll
        for (int kf = 0; kf < 2; ++kf) {
            const int koff = kf*64 + lq*16;
            bf16x8 bfr[4];
#pragma unroll
            for (int nf = 0; nf < 4; ++nf) {
                int r = waveN*64 + nf*16 + lr;
                bfr[nf] = *(const bf16x8*)(Bb + r*128 + koff);
            }
#pragma unroll
            for (int mf = 0; mf < 4; ++mf) {
                int r = waveM*64 + mf*16 + lr;
                bf16x8 afr = *(const bf16x8*)(Ab + r*128 + koff);
#pragma unroll
                for (int nf = 0; nf < 4; ++nf)
                    acc[mf][nf] = __builtin_amdgcn_mfma_f32_16x16x32_bf16(afr, bfr[nf], acc[mf][nf], 0, 0, 0);
            }
        }
    }
    // epilogue: tanh + Vv partial reduce over this 128-col slice
    float cv[4][4];
#pragma unroll
    for (int mf = 0; mf < 4; ++mf)
#pragma unroll
        for (int r = 0; r < 4; ++r) {
            int m = m0 + waveM*64 + mf*16 + lq*4 + r;
            cv[mf][r] = coverage[b*S_ + (m & 511)];
        }
    float e_acc[4][4] = {};
#pragma unroll
    for (int nf = 0; nf < 4; ++nf) {
        int n = n0 + waveN*64 + nf*16 + lr;
        float df = dec_feat[b*H_ + n];
        float wc = Wc[n];
        float vv = Vv[n];
#pragma unroll
        for (int mf = 0; mf < 4; ++mf)
#pragma unroll
            for (int r = 0; r < 4; ++r)
                e_acc[mf][r] += fast_tanh(acc[mf][nf][r] + df + cv[mf][r]*wc) * vv;
    }
#pragma unroll
    for (int msk = 1; msk < 16; msk <<= 1)
#pragma unroll
        for (int mf = 0; mf < 4; ++mf)
#pragma unroll
            for (int r = 0; r < 4; ++r)
                e_acc[mf][r] += __shfl_xor(e_acc[mf][r], msk);
    if (lr == 0) {
#pragma unroll
        for (int mf = 0; mf < 4; ++mf)
#pragma unroll
            for (int r = 0; r < 4; ++r)
                e_lds[waveN][waveM*64 + mf*16 + lq*4 + r] = e_acc[mf][r];
    }
    __syncthreads();
    if (t < 128)
        e_part[(size_t)nt*65536 + m0 + t] = e_lds[0][t] + e_lds[1][t];
}

// ---------------- K6 fallback (f32 staging, round-2 version) ----------------
__global__ __launch_bounds__(512,4) void attn_gemm_f32_kernel(
    const float* __restrict__ enc, const float* __restrict__ Wh,
    const float* __restrict__ dec_feat, const float* __restrict__ coverage,
    const float* __restrict__ Wc, const float* __restrict__ Vv,
    float* __restrict__ e_part)
{
    __shared__ char Ab[128*64*2];
    __shared__ char Bb[256*64*2];
    __shared__ float e_lds[4][128];
    const int t = threadIdx.x;
    const int wid = t >> 6, lane = t & 63;
    const int waveM = wid >> 2, waveN = wid & 3;
    const int lq = lane >> 4, lr = lane & 15;
    int bid = blockIdx.x;
    int wg = (bid & 7) * 256 + (bid >> 3);
    const int mt = wg >> 2, nt = wg & 3;
    const int m0 = mt * 128, n0 = nt * 256;
    const int b = m0 >> 9;
    const int arow = t >> 2, ak0 = (t & 3) * 16;
    const int brow = t >> 1, bk0 = (t & 1) * 32;
    f32x4 acc[4][4];
#pragma unroll
    for (int i = 0; i < 4; ++i)
#pragma unroll
        for (int j = 0; j < 4; ++j) acc[i][j] = (f32x4){0.f,0.f,0.f,0.f};
    for (int kc = 0; kc < 1024; kc += 64) {
        __syncthreads();
        {
            const float* src = enc + (size_t)(m0 + arow)*H_ + kc + ak0;
            float f[16];
            *(float4*)(f)    = *(const float4*)(src);
            *(float4*)(f+4)  = *(const float4*)(src+4);
            *(float4*)(f+8)  = *(const float4*)(src+8);
            *(float4*)(f+12) = *(const float4*)(src+12);
            char* dst = Ab + arow*128;
            int sw = (arow & 7) << 4;
            *(bf16x8*)(dst + ((ak0*2)      ^ sw)) = pack8(f);
            *(bf16x8*)(dst + ((ak0*2 + 16) ^ sw)) = pack8(f+8);
        }
        {
            const float* src = Wh + (size_t)(n0 + brow)*H_ + kc + bk0;
            char* dst = Bb + brow*128;
            int sw = (brow & 7) << 4;
            float f[16];
            *(float4*)(f)    = *(const float4*)(src);
            *(float4*)(f+4)  = *(const float4*)(src+4);
            *(float4*)(f+8)  = *(const float4*)(src+8);
            *(float4*)(f+12) = *(const float4*)(src+12);
            *(bf16x8*)(dst + ((bk0*2)      ^ sw)) = pack8(f);
            *(bf16x8*)(dst + ((bk0*2 + 16) ^ sw)) = pack8(f+8);
            *(float4*)(f)    = *(const float4*)(src+16);
            *(float4*)(f+4)  = *(const float4*)(src+20);
            *(float4*)(f+8)  = *(const float4*)(src+24);
            *(float4*)(f+12) = *(const float4*)(src+28);
            *(bf16x8*)(dst + ((bk0*2 + 32) ^ sw)) = pack8(f);
            *(bf16x8*)(dst + ((bk0*2 + 48) ^ sw)) = pack8(f+8);
        }
        __syncthreads();
#pragma unroll
        for (int kf = 0; kf < 2; ++kf) {
            const int koff = kf*64 + lq*16;
            bf16x8 bfr[4];
#pragma unroll
            for (int nf = 0; nf < 4; ++nf) {
                int r = waveN*64 + nf*16 + lr;
                bfr[nf] = *(const bf16x8*)(Bb + r*128 + (koff ^ ((r&7)<<4)));
            }
#pragma unroll
            for (int mf = 0; mf < 4; ++mf) {
                int r = waveM*64 + mf*16 + lr;
                bf16x8 afr = *(const bf16x8*)(Ab + r*128 + (koff ^ ((r&7)<<4)));
#pragma unroll
                for (int nf = 0; nf < 4; ++nf)
                    acc[mf][nf] = __builtin_amdgcn_mfma_f32_16x16x32_bf16(afr, bfr[nf], acc[mf][nf], 0, 0, 0);
            }
        }
    }
    float cv[4][4];
#pragma unroll
    for (int mf = 0; mf < 4; ++mf)
#pragma unroll
        for (int r = 0; r < 4; ++r) {
            int m = m0 + waveM*64 + mf*16 + lq*4 + r;
            cv[mf][r] = coverage[b*S_ + (m & 511)];
        }
    float e_acc[4][4] = {};
#pragma unroll
    for (int nf = 0; nf < 4; ++nf) {
        int n = n0 + waveN*64 + nf*16 + lr;
        float df = dec_feat[b*H_ + n];
        float wc = Wc[n];
        float vv = Vv[n];
#pragma unroll
        for (int mf = 0; mf < 4; ++mf)
#pragma unroll
            for (int r = 0; r < 4; ++r)
                e_acc[mf][r] += fast_tanh(acc[mf][nf][r] + df + cv[mf][r]*wc) * vv;
    }
#pragma unroll
    for (int msk = 1; msk < 16; msk <<= 1)
#pragma unroll
        for (int mf = 0; mf < 4; ++mf)
#pragma unroll
            for (int r = 0; r < 4; ++r)
                e_acc[mf][r] += __shfl_xor(e_acc[mf][r], msk);
    if (lr == 0) {
#pragma unroll
        for (int mf = 0; mf < 4; ++mf)
#pragma unroll
            for (int r = 0; r < 4; ++r)
                e_lds[waveN][waveM*64 + mf*16 + lq*4 + r] = e_acc[mf][r];
    }
    __syncthreads();
    if (t < 128)
        e_part[(size_t)nt*65536 + m0 + t] = e_lds[0][t] + e_lds[1][t] + e_lds[2][t] + e_lds[3][t];
}

// ---------------- K7: softmax over S + coverage (sums np partials) ----------------
__global__ __launch_bounds__(256) void attn_softmax_kernel(
    const float* __restrict__ e_part, int np, const float* __restrict__ mask,
    const float* __restrict__ cov, float* __restrict__ att,
    float* __restrict__ cov_next, float* __restrict__ loss)
{
    __shared__ float red[256];
    int b = blockIdx.x, t = threadIdx.x;
    int i1 = b*S_ + t, i2 = i1 + 256;
    float e1 = mask[i1], e2 = mask[i2];
    for (int p = 0; p < np; ++p) { e1 += e_part[(size_t)p*65536 + i1]; e2 += e_part[(size_t)p*65536 + i2]; }
    red[t] = fmaxf(e1, e2); __syncthreads();
    for (int o = 128; o > 0; o >>= 1) { if (t < o) red[t] = fmaxf(red[t], red[t+o]); __syncthreads(); }
    float m = red[0]; __syncthreads();
    float a1 = __expf(e1-m), a2 = __expf(e2-m);
    red[t] = a1+a2; __syncthreads();
    for (int o = 128; o > 0; o >>= 1) { if (t < o) red[t] += red[t+o]; __syncthreads(); }
    float inv = 1.f/red[0]; __syncthreads();
    a1 *= inv; a2 *= inv;
    att[i1] = a1; att[i2] = a2;
    float c1 = cov[i1]+a1, c2 = cov[i2]+a2;
    cov_next[i1] = c1; cov_next[i2] = c2;
    red[t] = fminf(a1,c1)+fminf(a2,c2); __syncthreads();
    for (int o = 128; o > 0; o >>= 1) { if (t < o) red[t] += red[t+o]; __syncthreads(); }
    if (t == 0) loss[b] = red[0];
}

// ---------------- K8: h_t = att @ enc (bf16 enc), s-split 4-way ----------------
__global__ __launch_bounds__(256) void context_part_bf16_kernel(
    const float* __restrict__ att, const unsigned short* __restrict__ encb, float* __restrict__ hq)
{
    __shared__ float asl[128];
    int b = blockIdx.x, sub = blockIdx.y;
    int hh = sub & 1, q = sub >> 1;
    int t = threadIdx.x;
    if (t < 128) asl[t] = att[b*S_ + q*128 + t];
    __syncthreads();
    int h = hh*512 + t*2;
    const unsigned short* ep = encb + (size_t)b*S_*H_ + (size_t)q*128*H_ + h;
    float a0 = 0.f, a1 = 0.f;
#pragma unroll 4
    for (int s = 0; s < 128; ++s) {
        union { unsigned u; unsigned short s2[2]; } v;
        v.u = *(const unsigned*)(ep + (size_t)s*H_);
        float w = asl[s];
        a0 += w*bf2f(v.s2[0]); a1 += w*bf2f(v.s2[1]);
    }
    float* o = hq + ((size_t)q*B_ + b)*H_ + h;
    o[0] = a0; o[1] = a1;
}

__global__ __launch_bounds__(256) void context_part_f32_kernel(
    const float* __restrict__ att, const float* __restrict__ enc, float* __restrict__ hq)
{
    __shared__ float asl[128];
    int b = blockIdx.x, sub = blockIdx.y;
    int hh = sub & 1, q = sub >> 1;
    int t = threadIdx.x;
    if (t < 128) asl[t] = att[b*S_ + q*128 + t];
    __syncthreads();
    int h = hh*512 + t*2;
    const float* ep = enc + (size_t)b*S_*H_ + (size_t)q*128*H_ + h;
    float a0 = 0.f, a1 = 0.f;
#pragma unroll 4
    for (int s = 0; s < 128; ++s) {
        float2 v = *(const float2*)(ep + (size_t)s*H_);
        float w = asl[s];
        a0 += w*v.x; a1 += w*v.y;
    }
    float* o = hq + ((size_t)q*B_ + b)*H_ + h;
    o[0] = a0; o[1] = a1;
}

// ---------------- K9: p_gen + build A2=[s_t,h_t] ----------------
__global__ __launch_bounds__(256) void pgen_kernel(
    const float* __restrict__ h_t, const float* __restrict__ s_t, const float* __restrict__ x,
    const float* __restrict__ pgW, const float* __restrict__ pgb,
    float* __restrict__ pgen, float* __restrict__ A2)
{
    __shared__ float red[256];
    int b = blockIdx.x, t = threadIdx.x;
    float s = 0.f;
#pragma unroll
    for (int i = 0; i < 12; ++i) {
        int j = t + i*256;
        float v = (j < 1024) ? h_t[b*1024+j] : (j < 2048 ? s_t[b*1024 + j-1024] : x[b*1024 + j-2048]);
        s += v * pgW[j];
    }
    red[t] = s; __syncthreads();
    for (int o = 128; o > 0; o >>= 1) { if (t < o) red[t] += red[t+o]; __syncthreads(); }
    if (t == 0) {
        float p = 1.f/(1.f+__expf(-(red[0] + pgb[0])));
        pgen[b] = fmaxf(p, EPS_);
    }
#pragma unroll
    for (int i = 0; i < 8; ++i) {
        int j = t + i*256;
        A2[(size_t)b*2048 + j] = (j < 1024) ? s_t[b*1024+j] : h_t[b*1024+j-1024];
    }
}

// ---------------- K12: vocab softmax in place ----------------
__global__ __launch_bounds__(1024) void vocab_softmax_kernel(
    float* __restrict__ out0, const float* __restrict__ pgen)
{
    __shared__ float rm[1024], rl[1024];
    int b = blockIdx.x, t = threadIdx.x;
    float* row = out0 + (size_t)b*VE_;
    float m = -1e30f, l = 0.f;
    for (int i = t; i < V_; i += 1024) {
        float xv = row[i];
        if (xv > m) { l = l*__expf(m-xv) + 1.f; m = xv; }
        else l += __expf(xv-m);
    }
    rm[t] = m; rl[t] = l; __syncthreads();
    for (int o = 512; o > 0; o >>= 1) {
        if (t < o) {
            float m1 = rm[t], m2 = rm[t+o];
            float M = fmaxf(m1, m2);
            rl[t] = rl[t]*__expf(m1-M) + rl[t+o]*__expf(m2-M);
            rm[t] = M;
        }
        __syncthreads();
    }
    float M = rm[0], inv = pgen[b]/rl[0];
    for (int i = t; i < V_; i += 1024)
        row[i] = __expf(row[i]-M)*inv;
    for (int i = V_ + t; i < VE_; i += 1024)
        row[i] = 0.f;
}

// ---------------- K13: scatter-add copy distribution ----------------
__global__ __launch_bounds__(256) void scatter_kernel(
    const int* __restrict__ ebev, const float* __restrict__ att,
    const float* __restrict__ pgen, float* __restrict__ out0)
{
    int i = blockIdx.x*256 + threadIdx.x;
    int b = i >> 9;
    float val = (1.f - pgen[b]) * att[i];
    int col = ebev[i];
    atomicAdd(out0 + (size_t)b*VE_ + col, val);
}

// ---------------- K14: clip + log in place ----------------
__global__ __launch_bounds__(256) void log_kernel(float* __restrict__ out0)
{
    int i = (blockIdx.x*256 + threadIdx.x) * 4;
    if (i >= B_*VE_) return;
    float4 v = *(float4*)(out0 + i);
    v.x = __logf(fmaxf(v.x, EPS_));
    v.y = __logf(fmaxf(v.y, EPS_));
    v.z = __logf(fmaxf(v.z, EPS_));
    v.w = __logf(fmaxf(v.w, EPS_));
    *(float4*)(out0 + i) = v;
}

extern "C" void kernel_launch(void* const* d_in, const int* in_sizes, int n_in,
                              void* d_out, int out_size, void* d_ws, size_t ws_size,
                              hipStream_t stream) {
    const int*   tok        = (const int*)d_in[0];
    const float* dec_hidden = (const float*)d_in[1];
    const float* enc        = (const float*)d_in[2];
    const float* mask       = (const float*)d_in[3];
    const float* ctx1       = (const float*)d_in[4];
    const int*   ebev       = (const int*)d_in[5];
    const float* cov        = (const float*)d_in[7];
    const float* embed      = (const float*)d_in[8];
    const float* ln_g       = (const float*)d_in[9];
    const float* ln_b       = (const float*)d_in[10];
    const float* xc_W       = (const float*)d_in[11];
    const float* xc_b       = (const float*)d_in[12];
    const float* W_ih       = (const float*)d_in[13];
    const float* W_hh       = (const float*)d_in[14];
    const float* b_ih       = (const float*)d_in[15];
    const float* b_hh       = (const float*)d_in[16];
    const float* Wh         = (const float*)d_in[17];
    const float* Ws         = (const float*)d_in[18];
    const float* Ws_b       = (const float*)d_in[19];
    const float* Wc         = (const float*)d_in[20];
    const float* Vv         = (const float*)d_in[21];
    const float* pg_W       = (const float*)d_in[22];
    const float* pg_b       = (const float*)d_in[23];
    const float* out1_W     = (const float*)d_in[24];
    const float* out1_b     = (const float*)d_in[25];
    const float* out2_W     = (const float*)d_in[26];
    const float* out2_b     = (const float*)d_in[27];

    float* out      = (float*)d_out;
    float* s_t      = out + 6464000;
    float* h_t      = out + 6595072;
    float* cov_next = out + 6726144;
    float* loss     = out + 6791680;

    // bf16 path: enc_bf = 67,108,864 bf16 = 33,554,432 f32 slots;
    // wh_bf = 1,048,576 bf16 = 524,288 f32 slots (round-3 bug: was 262,144 ->
    // x_cat overlapped wh_bf rows 512..1023 and corrupted the attn B matrix)
    const size_t ENC_SLOTS = 33554432, WH_SLOTS = 524288;
    const size_t need = (ENC_SLOTS + WH_SLOTS + 5177472) * 4;
    const bool bf16_path = (ws_size >= need);

    float* wsf = (float*)d_ws;
    unsigned short* enc_bf = (unsigned short*)d_ws;
    unsigned short* wh_bf  = (unsigned short*)(wsf + ENC_SLOTS);
    float* base     = bf16_path ? (wsf + ENC_SLOTS + WH_SLOTS) : wsf;
    float* x_cat    = base;             // 262144
    float* x_part   = base + 262144;    // 4 x 131072
    float* x        = base + 786432;    // 131072
    float* gx_part  = base + 917504;    // 2 x 393216
    float* gh_part  = base + 1703936;   // 2 x 393216
    float* ds_part  = base + 2490368;   // 4 x 131072
    float* dec_feat = base + 3014656;   // 131072
    float* e_part   = base + 3145728;   // 8 x 65536
    float* att      = base + 3670016;   // 65536
    float* pgen     = base + 3735552;   // 128
    float* A2       = base + 3735680;   // 262144
    float* h2_part  = base + 3997824;   // 4 x 131072
    float* h2       = base + 4522112;   // 131072
    float* hq       = base + 4653184;   // 4 x 131072

    if (bf16_path) {
        cvt_bf16_kernel<<<32768, 256, 0, stream>>>(enc, enc_bf);
        cvt_bf16_kernel<<<512, 256, 0, stream>>>(Wh, wh_bf);
    }
    embed_ln_kernel<<<128, 256, 0, stream>>>(tok, embed, ln_g, ln_b, ctx1, x_cat);
    gemm128_kernel<<<dim3(16,4), 256, 0, stream>>>(x_cat, xc_W, xc_b, x_part, 1024, 2048, 1024, 512);
    reduce4_kernel<<<512, 256, 0, stream>>>(x_part, x, 131072);
    gemm128_kernel<<<dim3(48,2), 256, 0, stream>>>(x, W_ih, b_ih, gx_part, 3072, 1024, 3072, 512);
    gemm128_kernel<<<dim3(48,2), 256, 0, stream>>>(dec_hidden, W_hh, b_hh, gh_part, 3072, 1024, 3072, 512);
    gru_gate_kernel<<<512, 256, 0, stream>>>(gx_part, gh_part, dec_hidden, s_t);
    gemm128_kernel<<<dim3(16,4), 256, 0, stream>>>(s_t, Ws, Ws_b, ds_part, 1024, 1024, 1024, 256);
    reduce4_kernel<<<512, 256, 0, stream>>>(ds_part, dec_feat, 131072);

    int npart;
    if (bf16_path) {
        attn_gemm_bf16_kernel<<<4096, 256, 0, stream>>>(enc_bf, wh_bf, dec_feat, cov, Wc, Vv, e_part);
        npart = 8;
    } else {
        attn_gemm_f32_kernel<<<2048, 512, 0, stream>>>(enc, Wh, dec_feat, cov, Wc, Vv, e_part);
        npart = 4;
    }
    attn_softmax_kernel<<<128, 256, 0, stream>>>(e_part, npart, mask, cov, att, cov_next, loss);
    dim3 g8(128, 8);
    if (bf16_path)
        context_part_bf16_kernel<<<g8, 256, 0, stream>>>(att, enc_bf, hq);
    else
        context_part_f32_kernel<<<g8, 256, 0, stream>>>(att, enc, hq);
    reduce4_kernel<<<512, 256, 0, stream>>>(hq, h_t, 131072);
    pgen_kernel<<<128, 256, 0, stream>>>(h_t, s_t, x, pg_W, pg_b, pgen, A2);
    gemm128_kernel<<<dim3(16,4), 256, 0, stream>>>(A2, out1_W, out1_b, h2_part, 1024, 2048, 1024, 512);
    reduce4_kernel<<<512, 256, 0, stream>>>(h2_part, h2, 131072);
    gemm128_kernel<<<dim3(782,1), 256, 0, stream>>>(h2, out2_W, out2_b, out, 50000, 1024, VE_, 1024);
    vocab_softmax_kernel<<<128, 1024, 0, stream>>>(out, pgen);
    scatter_kernel<<<256, 256, 0, stream>>>(ebev, att, pgen, out);
    log_kernel<<<6313, 256, 0, stream>>>(out);
}

// Round 5
// 528.237 us; speedup vs baseline: 1.9442x; 1.0368x over previous
//
#include <hip/hip_runtime.h>
#include <hip/hip_bf16.h>
#include <stdint.h>

#define B_ 128
#define S_ 512
#define H_ 1024
#define E_ 1024
#define V_ 50000
#define EXTRA_ 500
#define VE_ 50500
#define EPS_ 1e-8f

typedef __attribute__((ext_vector_type(4))) float f32x4;
typedef __attribute__((ext_vector_type(8))) short bf16x8;

__device__ __forceinline__ unsigned short f2bf(float f) {
    unsigned u = __builtin_bit_cast(unsigned, f);
    u = (u + 0x7FFFu + ((u >> 16) & 1u)) >> 16;
    return (unsigned short)u;
}

__device__ __forceinline__ bf16x8 pack8(const float* f) {
    union { bf16x8 v; unsigned short s[8]; } u;
#pragma unroll
    for (int i = 0; i < 8; ++i) u.s[i] = f2bf(f[i]);
    return u.v;
}

__device__ __forceinline__ float bf2f(unsigned short s) {
    unsigned u = (unsigned)s << 16;
    return __builtin_bit_cast(float, u);
}

__device__ __forceinline__ float fast_tanh(float x) {
    x = fminf(fmaxf(x, -15.f), 15.f);
    float e = __expf(2.f * x);
    return __fdividef(e - 1.f, e + 1.f);
}

// async global->LDS, 16 bytes per lane; lds dest is wave-uniform-base + lane*16
__device__ __forceinline__ void gload16(const void* g, void* l) {
    __builtin_amdgcn_global_load_lds(
        reinterpret_cast<const __attribute__((address_space(1))) unsigned int*>(
            reinterpret_cast<uintptr_t>(g)),
        reinterpret_cast<__attribute__((address_space(3))) unsigned int*>(
            reinterpret_cast<uintptr_t>(l)),
        16, 0, 0);
}

// ---------------- K0: f32 -> bf16 convert ----------------
__global__ __launch_bounds__(256) void cvt_bf16_kernel(const float* __restrict__ in,
                                                       unsigned short* __restrict__ out) {
    int i = (blockIdx.x * 256 + threadIdx.x) * 8;
    float f[8];
    *(float4*)f     = *(const float4*)(in + i);
    *(float4*)(f+4) = *(const float4*)(in + i + 4);
    union { uint4 v; unsigned short s[8]; } u;
#pragma unroll
    for (int j = 0; j < 8; ++j) u.s[j] = f2bf(f[j]);
    *(uint4*)(out + i) = u.v;
}

// ---------------- K1: embedding + layernorm + concat ----------------
__global__ __launch_bounds__(256) void embed_ln_kernel(
    const int* __restrict__ tok, const float* __restrict__ embed,
    const float* __restrict__ g, const float* __restrict__ beta,
    const float* __restrict__ ctx, float* __restrict__ x_cat)
{
    __shared__ float red[256];
    int b = blockIdx.x, t = threadIdx.x;
    const float* row = embed + (size_t)tok[b] * E_;
    float v[4];
    float s = 0.f;
#pragma unroll
    for (int i = 0; i < 4; ++i) { v[i] = row[t + i*256]; s += v[i]; }
    red[t] = s; __syncthreads();
    for (int o = 128; o > 0; o >>= 1) { if (t < o) red[t] += red[t+o]; __syncthreads(); }
    float mu = red[0] * (1.f/E_);
    __syncthreads();
    s = 0.f;
#pragma unroll
    for (int i = 0; i < 4; ++i) { float d = v[i]-mu; s += d*d; }
    red[t] = s; __syncthreads();
    for (int o = 128; o > 0; o >>= 1) { if (t < o) red[t] += red[t+o]; __syncthreads(); }
    float inv = rsqrtf(red[0]*(1.f/E_) + 1e-5f);
    float* xrow = x_cat + (size_t)b * 2048;
#pragma unroll
    for (int i = 0; i < 4; ++i) {
        int j = t + i*256;
        xrow[j] = (v[i]-mu)*inv*g[j] + beta[j];
        xrow[1024 + j] = ctx[b*1024 + j];
    }
}

// ---------------- generic M=128 GEMM with optional K-split ----------------
__global__ __launch_bounds__(256) void gemm128_kernel(
    const float* __restrict__ A, const float* __restrict__ W,
    const float* __restrict__ bias, float* __restrict__ C,
    int N, int K, int ldc, int kchunk)
{
    __shared__ char Ab[128*64*2];
    __shared__ char Wb[64*64*2];
    const int t = threadIdx.x;
    const int wid = t >> 6, lane = t & 63;
    const int waveM = wid >> 1, waveN = wid & 1;
    const int lq = lane >> 4, lr = lane & 15;
    const int n0 = blockIdx.x * 64;
    const int kbeg = blockIdx.y * kchunk, kend = kbeg + kchunk;
    f32x4 acc[4][2];
#pragma unroll
    for (int i = 0; i < 4; ++i)
#pragma unroll
        for (int j = 0; j < 2; ++j) acc[i][j] = (f32x4){0.f,0.f,0.f,0.f};
    for (int kc = kbeg; kc < kend; kc += 64) {
        __syncthreads();
#pragma unroll
        for (int i = 0; i < 4; ++i) {
            int c = t + i*256;
            int row = c >> 3, k8 = (c & 7) << 3;
            const float* src = A + (size_t)row*K + kc + k8;
            float f[8];
            *(float4*)f     = *(const float4*)src;
            *(float4*)(f+4) = *(const float4*)(src+4);
            int byte = row*128 + ((k8*2) ^ ((row&7)<<4));
            *(bf16x8*)(Ab + byte) = pack8(f);
        }
#pragma unroll
        for (int i = 0; i < 2; ++i) {
            int c = t + i*256;
            int row = c >> 3, k8 = (c & 7) << 3;
            int n = n0 + row;
            float f[8] = {0,0,0,0,0,0,0,0};
            if (n < N) {
                const float* src = W + (size_t)n*K + kc + k8;
                *(float4*)f     = *(const float4*)src;
                *(float4*)(f+4) = *(const float4*)(src+4);
            }
            int byte = row*128 + ((k8*2) ^ ((row&7)<<4));
            *(bf16x8*)(Wb + byte) = pack8(f);
        }
        __syncthreads();
#pragma unroll
        for (int kf = 0; kf < 2; ++kf) {
            int kk2 = (kf*32 + (lq<<3)) * 2;
            bf16x8 bfr[2];
#pragma unroll
            for (int nf = 0; nf < 2; ++nf) {
                int r = waveN*32 + nf*16 + lr;
                bfr[nf] = *(const bf16x8*)(Wb + r*128 + (kk2 ^ ((r&7)<<4)));
            }
#pragma unroll
            for (int mf = 0; mf < 4; ++mf) {
                int r = waveM*64 + mf*16 + lr;
                bf16x8 afr = *(const bf16x8*)(Ab + r*128 + (kk2 ^ ((r&7)<<4)));
#pragma unroll
                for (int nf = 0; nf < 2; ++nf)
                    acc[mf][nf] = __builtin_amdgcn_mfma_f32_16x16x32_bf16(afr, bfr[nf], acc[mf][nf], 0, 0, 0);
            }
        }
    }
    float* Cp = C + (size_t)blockIdx.y * 128 * (size_t)ldc;
    bool addb = (bias != nullptr) && (blockIdx.y == 0);
#pragma unroll
    for (int mf = 0; mf < 4; ++mf)
#pragma unroll
        for (int nf = 0; nf < 2; ++nf) {
            int n = n0 + waveN*32 + nf*16 + lr;
            if (n < N) {
                float bv = addb ? bias[n] : 0.f;
#pragma unroll
                for (int r = 0; r < 4; ++r) {
                    int m = waveM*64 + mf*16 + (lq<<2) + r;
                    Cp[(size_t)m*ldc + n] = acc[mf][nf][r] + bv;
                }
            }
        }
}

// ---------------- reduce 4 partial slices ----------------
__global__ __launch_bounds__(256) void reduce4_kernel(
    const float* __restrict__ in, float* __restrict__ out, int len)
{
    int i = blockIdx.x*256 + threadIdx.x;
    if (i < len) out[i] = in[i] + in[len+i] + in[2*len+i] + in[3*len+i];
}

// ---------------- GRU gates (reads 2-way K-split partials) ----------------
__global__ __launch_bounds__(256) void gru_gate_kernel(
    const float* __restrict__ gxp, const float* __restrict__ ghp,
    const float* __restrict__ h0, float* __restrict__ s_t)
{
    int i = blockIdx.x*256 + threadIdx.x;
    int b = i >> 10, h = i & 1023;
    const float* gx0 = gxp + (size_t)b*3072;
    const float* gx1 = gx0 + 393216;
    const float* gh0 = ghp + (size_t)b*3072;
    const float* gh1 = gh0 + 393216;
    float grx = gx0[h] + gx1[h],        grh = gh0[h] + gh1[h];
    float gzx = gx0[h+1024]+gx1[h+1024], gzh = gh0[h+1024]+gh1[h+1024];
    float gnx = gx0[h+2048]+gx1[h+2048], gnh = gh0[h+2048]+gh1[h+2048];
    float r = 1.f/(1.f+__expf(-(grx + grh)));
    float z = 1.f/(1.f+__expf(-(gzx + gzh)));
    float n = fast_tanh(gnx + r*gnh);
    s_t[i] = (1.f-z)*n + z*h0[i];
}

// ---------------- K6 (bf16): fused attention-score GEMM, m97 structure + T2 swizzle ----
// BM=128,BN=128,BK=64; 4 waves (2x2); grid 512*8=4096, global_load_lds staging.
// T2: gload_lds writes linearly, so the LDS swizzle is realized by pre-swizzling the
// GLOBAL source k-unit (rule 21): LDS[row][c16] holds A[row][c16 ^ (row&7)]; reads
// XOR the byte offset with (row&7)<<4. Bank spread: 16-way -> 2-way (free, m136).
// e_lds aliased into Ab (dead after K-loop) => block LDS exactly 32 KiB.
__global__ __launch_bounds__(256,4) void attn_gemm_bf16_kernel(
    const unsigned short* __restrict__ encb,   // [65536,1024] bf16
    const unsigned short* __restrict__ whb,    // [1024,1024] bf16
    const float* __restrict__ dec_feat, const float* __restrict__ coverage,
    const float* __restrict__ Wc, const float* __restrict__ Vv,
    float* __restrict__ e_part)                // [8][65536]
{
    __shared__ char Ab[128*128];   // [128 rows][64 bf16], source-pre-swizzled
    __shared__ char Bb[128*128];
    const int t = threadIdx.x;
    const int wid = t >> 6, lane = t & 63;
    const int waveM = wid >> 1, waveN = wid & 1;
    const int lq = lane >> 4, lr = lane & 15;
    // XCD-chunked bijective swizzle; nt fast so 8 n-tiles of an m-panel co-run on one XCD
    int bid = blockIdx.x;
    int wg = (bid & 7) * 512 + (bid >> 3);
    const int nt = wg & 7, mt = wg >> 3;
    const int m0 = mt * 128, n0 = nt * 128;
    const int b = m0 >> 9;

    const int grow = wid*8 + (lane >> 3);          // staging row within 32-row group
    const int gk16 = (lane & 7) ^ ((lane >> 3) & 7);  // pre-swizzled 16B unit (T2)
    const unsigned short* asrc = encb + (size_t)(m0 + grow)*H_ + gk16*8;
    const unsigned short* bsrc = whb  + (size_t)(n0 + grow)*H_ + gk16*8;
    char* aldst = Ab + wid*1024;
    char* bldst = Bb + wid*1024;

    f32x4 acc[4][4];
#pragma unroll
    for (int i = 0; i < 4; ++i)
#pragma unroll
        for (int j = 0; j < 4; ++j) acc[i][j] = (f32x4){0.f,0.f,0.f,0.f};

    for (int kc = 0; kc < 1024; kc += 64) {
        __syncthreads();
#pragma unroll
        for (int i = 0; i < 4; ++i) {
            gload16(asrc + kc + i*32*H_, aldst + i*4096);
            gload16(bsrc + kc + i*32*H_, bldst + i*4096);
        }
        __syncthreads();
#pragma unroll
        for (int kf = 0; kf < 2; ++kf) {
            const int koff = kf*64 + lq*16;
            bf16x8 bfr[4];
#pragma unroll
            for (int nf = 0; nf < 4; ++nf) {
                int r = waveN*64 + nf*16 + lr;
                bfr[nf] = *(const bf16x8*)(Bb + r*128 + (koff ^ ((r&7)<<4)));
            }
#pragma unroll
            for (int mf = 0; mf < 4; ++mf) {
                int r = waveM*64 + mf*16 + lr;
                bf16x8 afr = *(const bf16x8*)(Ab + r*128 + (koff ^ ((r&7)<<4)));
#pragma unroll
                for (int nf = 0; nf < 4; ++nf)
                    acc[mf][nf] = __builtin_amdgcn_mfma_f32_16x16x32_bf16(afr, bfr[nf], acc[mf][nf], 0, 0, 0);
            }
        }
    }
    // epilogue: tanh + Vv partial reduce over this 128-col slice
    float cv[4][4];
#pragma unroll
    for (int mf = 0; mf < 4; ++mf)
#pragma unroll
        for (int r = 0; r < 4; ++r) {
            int m = m0 + waveM*64 + mf*16 + lq*4 + r;
            cv[mf][r] = coverage[b*S_ + (m & 511)];
        }
    float e_acc[4][4] = {};
#pragma unroll
    for (int nf = 0; nf < 4; ++nf) {
        int n = n0 + waveN*64 + nf*16 + lr;
        float df = dec_feat[b*H_ + n];
        float wc = Wc[n];
        float vv = Vv[n];
#pragma unroll
        for (int mf = 0; mf < 4; ++mf)
#pragma unroll
            for (int r = 0; r < 4; ++r)
                e_acc[mf][r] += fast_tanh(acc[mf][nf][r] + df + cv[mf][r]*wc) * vv;
    }
#pragma unroll
    for (int msk = 1; msk < 16; msk <<= 1)
#pragma unroll
        for (int mf = 0; mf < 4; ++mf)
#pragma unroll
            for (int r = 0; r < 4; ++r)
                e_acc[mf][r] += __shfl_xor(e_acc[mf][r], msk);
    __syncthreads();                 // all waves done reading Ab: safe to alias
    float* el = (float*)Ab;          // [2][128] epilogue buffer aliased into Ab
    if (lr == 0) {
#pragma unroll
        for (int mf = 0; mf < 4; ++mf)
#pragma unroll
            for (int r = 0; r < 4; ++r)
                el[waveN*128 + waveM*64 + mf*16 + lq*4 + r] = e_acc[mf][r];
    }
    __syncthreads();
    if (t < 128)
        e_part[(size_t)nt*65536 + m0 + t] = el[t] + el[128 + t];
}

// ---------------- K6 fallback (f32 staging, round-2 version) ----------------
__global__ __launch_bounds__(512,4) void attn_gemm_f32_kernel(
    const float* __restrict__ enc, const float* __restrict__ Wh,
    const float* __restrict__ dec_feat, const float* __restrict__ coverage,
    const float* __restrict__ Wc, const float* __restrict__ Vv,
    float* __restrict__ e_part)
{
    __shared__ char Ab[128*64*2];
    __shared__ char Bb[256*64*2];
    __shared__ float e_lds[4][128];
    const int t = threadIdx.x;
    const int wid = t >> 6, lane = t & 63;
    const int waveM = wid >> 2, waveN = wid & 3;
    const int lq = lane >> 4, lr = lane & 15;
    int bid = blockIdx.x;
    int wg = (bid & 7) * 256 + (bid >> 3);
    const int mt = wg >> 2, nt = wg & 3;
    const int m0 = mt * 128, n0 = nt * 256;
    const int b = m0 >> 9;
    const int arow = t >> 2, ak0 = (t & 3) * 16;
    const int brow = t >> 1, bk0 = (t & 1) * 32;
    f32x4 acc[4][4];
#pragma unroll
    for (int i = 0; i < 4; ++i)
#pragma unroll
        for (int j = 0; j < 4; ++j) acc[i][j] = (f32x4){0.f,0.f,0.f,0.f};
    for (int kc = 0; kc < 1024; kc += 64) {
        __syncthreads();
        {
            const float* src = enc + (size_t)(m0 + arow)*H_ + kc + ak0;
            float f[16];
            *(float4*)(f)    = *(const float4*)(src);
            *(float4*)(f+4)  = *(const float4*)(src+4);
            *(float4*)(f+8)  = *(const float4*)(src+8);
            *(float4*)(f+12) = *(const float4*)(src+12);
            char* dst = Ab + arow*128;
            int sw = (arow & 7) << 4;
            *(bf16x8*)(dst + ((ak0*2)      ^ sw)) = pack8(f);
            *(bf16x8*)(dst + ((ak0*2 + 16) ^ sw)) = pack8(f+8);
        }
        {
            const float* src = Wh + (size_t)(n0 + brow)*H_ + kc + bk0;
            char* dst = Bb + brow*128;
            int sw = (brow & 7) << 4;
            float f[16];
            *(float4*)(f)    = *(const float4*)(src);
            *(float4*)(f+4)  = *(const float4*)(src+4);
            *(float4*)(f+8)  = *(const float4*)(src+8);
            *(float4*)(f+12) = *(const float4*)(src+12);
            *(bf16x8*)(dst + ((bk0*2)      ^ sw)) = pack8(f);
            *(bf16x8*)(dst + ((bk0*2 + 16) ^ sw)) = pack8(f+8);
            *(float4*)(f)    = *(const float4*)(src+16);
            *(float4*)(f+4)  = *(const float4*)(src+20);
            *(float4*)(f+8)  = *(const float4*)(src+24);
            *(float4*)(f+12) = *(const float4*)(src+28);
            *(bf16x8*)(dst + ((bk0*2 + 32) ^ sw)) = pack8(f);
            *(bf16x8*)(dst + ((bk0*2 + 48) ^ sw)) = pack8(f+8);
        }
        __syncthreads();
#pragma unroll
        for (int kf = 0; kf < 2; ++kf) {
            const int koff = kf*64 + lq*16;
            bf16x8 bfr[4];
#pragma unroll
            for (int nf = 0; nf < 4; ++nf) {
                int r = waveN*64 + nf*16 + lr;
                bfr[nf] = *(const bf16x8*)(Bb + r*128 + (koff ^ ((r&7)<<4)));
            }
#pragma unroll
            for (int mf = 0; mf < 4; ++mf) {
                int r = waveM*64 + mf*16 + lr;
                bf16x8 afr = *(const bf16x8*)(Ab + r*128 + (koff ^ ((r&7)<<4)));
#pragma unroll
                for (int nf = 0; nf < 4; ++nf)
                    acc[mf][nf] = __builtin_amdgcn_mfma_f32_16x16x32_bf16(afr, bfr[nf], acc[mf][nf], 0, 0, 0);
            }
        }
    }
    float cv[4][4];
#pragma unroll
    for (int mf = 0; mf < 4; ++mf)
#pragma unroll
        for (int r = 0; r < 4; ++r) {
            int m = m0 + waveM*64 + mf*16 + lq*4 + r;
            cv[mf][r] = coverage[b*S_ + (m & 511)];
        }
    float e_acc[4][4] = {};
#pragma unroll
    for (int nf = 0; nf < 4; ++nf) {
        int n = n0 + waveN*64 + nf*16 + lr;
        float df = dec_feat[b*H_ + n];
        float wc = Wc[n];
        float vv = Vv[n];
#pragma unroll
        for (int mf = 0; mf < 4; ++mf)
#pragma unroll
            for (int r = 0; r < 4; ++r)
                e_acc[mf][r] += fast_tanh(acc[mf][nf][r] + df + cv[mf][r]*wc) * vv;
    }
#pragma unroll
    for (int msk = 1; msk < 16; msk <<= 1)
#pragma unroll
        for (int mf = 0; mf < 4; ++mf)
#pragma unroll
            for (int r = 0; r < 4; ++r)
                e_acc[mf][r] += __shfl_xor(e_acc[mf][r], msk);
    if (lr == 0) {
#pragma unroll
        for (int mf = 0; mf < 4; ++mf)
#pragma unroll
            for (int r = 0; r < 4; ++r)
                e_lds[waveN][waveM*64 + mf*16 + lq*4 + r] = e_acc[mf][r];
    }
    __syncthreads();
    if (t < 128)
        e_part[(size_t)nt*65536 + m0 + t] = e_lds[0][t] + e_lds[1][t] + e_lds[2][t] + e_lds[3][t];
}

// ---------------- K7: softmax over S + coverage (sums np partials) ----------------
__global__ __launch_bounds__(256) void attn_softmax_kernel(
    const float* __restrict__ e_part, int np, const float* __restrict__ mask,
    const float* __restrict__ cov, float* __restrict__ att,
    float* __restrict__ cov_next, float* __restrict__ loss)
{
    __shared__ float red[256];
    int b = blockIdx.x, t = threadIdx.x;
    int i1 = b*S_ + t, i2 = i1 + 256;
    float e1 = mask[i1], e2 = mask[i2];
    for (int p = 0; p < np; ++p) { e1 += e_part[(size_t)p*65536 + i1]; e2 += e_part[(size_t)p*65536 + i2]; }
    red[t] = fmaxf(e1, e2); __syncthreads();
    for (int o = 128; o > 0; o >>= 1) { if (t < o) red[t] = fmaxf(red[t], red[t+o]); __syncthreads(); }
    float m = red[0]; __syncthreads();
    float a1 = __expf(e1-m), a2 = __expf(e2-m);
    red[t] = a1+a2; __syncthreads();
    for (int o = 128; o > 0; o >>= 1) { if (t < o) red[t] += red[t+o]; __syncthreads(); }
    float inv = 1.f/red[0]; __syncthreads();
    a1 *= inv; a2 *= inv;
    att[i1] = a1; att[i2] = a2;
    float c1 = cov[i1]+a1, c2 = cov[i2]+a2;
    cov_next[i1] = c1; cov_next[i2] = c2;
    red[t] = fminf(a1,c1)+fminf(a2,c2); __syncthreads();
    for (int o = 128; o > 0; o >>= 1) { if (t < o) red[t] += red[t+o]; __syncthreads(); }
    if (t == 0) loss[b] = red[0];
}

// ---------------- K8: h_t = att @ enc (bf16 enc), s-split 4-way ----------------
__global__ __launch_bounds__(256) void context_part_bf16_kernel(
    const float* __restrict__ att, const unsigned short* __restrict__ encb, float* __restrict__ hq)
{
    __shared__ float asl[128];
    int b = blockIdx.x, sub = blockIdx.y;
    int hh = sub & 1, q = sub >> 1;
    int t = threadIdx.x;
    if (t < 128) asl[t] = att[b*S_ + q*128 + t];
    __syncthreads();
    int h = hh*512 + t*2;
    const unsigned short* ep = encb + (size_t)b*S_*H_ + (size_t)q*128*H_ + h;
    float a0 = 0.f, a1 = 0.f;
#pragma unroll 4
    for (int s = 0; s < 128; ++s) {
        union { unsigned u; unsigned short s2[2]; } v;
        v.u = *(const unsigned*)(ep + (size_t)s*H_);
        float w = asl[s];
        a0 += w*bf2f(v.s2[0]); a1 += w*bf2f(v.s2[1]);
    }
    float* o = hq + ((size_t)q*B_ + b)*H_ + h;
    o[0] = a0; o[1] = a1;
}

__global__ __launch_bounds__(256) void context_part_f32_kernel(
    const float* __restrict__ att, const float* __restrict__ enc, float* __restrict__ hq)
{
    __shared__ float asl[128];
    int b = blockIdx.x, sub = blockIdx.y;
    int hh = sub & 1, q = sub >> 1;
    int t = threadIdx.x;
    if (t < 128) asl[t] = att[b*S_ + q*128 + t];
    __syncthreads();
    int h = hh*512 + t*2;
    const float* ep = enc + (size_t)b*S_*H_ + (size_t)q*128*H_ + h;
    float a0 = 0.f, a1 = 0.f;
#pragma unroll 4
    for (int s = 0; s < 128; ++s) {
        float2 v = *(const float2*)(ep + (size_t)s*H_);
        float w = asl[s];
        a0 += w*v.x; a1 += w*v.y;
    }
    float* o = hq + ((size_t)q*B_ + b)*H_ + h;
    o[0] = a0; o[1] = a1;
}

// ---------------- K9: p_gen + build A2=[s_t,h_t] ----------------
__global__ __launch_bounds__(256) void pgen_kernel(
    const float* __restrict__ h_t, const float* __restrict__ s_t, const float* __restrict__ x,
    const float* __restrict__ pgW, const float* __restrict__ pgb,
    float* __restrict__ pgen, float* __restrict__ A2)
{
    __shared__ float red[256];
    int b = blockIdx.x, t = threadIdx.x;
    float s = 0.f;
#pragma unroll
    for (int i = 0; i < 12; ++i) {
        int j = t + i*256;
        float v = (j < 1024) ? h_t[b*1024+j] : (j < 2048 ? s_t[b*1024 + j-1024] : x[b*1024 + j-2048]);
        s += v * pgW[j];
    }
    red[t] = s; __syncthreads();
    for (int o = 128; o > 0; o >>= 1) { if (t < o) red[t] += red[t+o]; __syncthreads(); }
    if (t == 0) {
        float p = 1.f/(1.f+__expf(-(red[0] + pgb[0])));
        pgen[b] = fmaxf(p, EPS_);
    }
#pragma unroll
    for (int i = 0; i < 8; ++i) {
        int j = t + i*256;
        A2[(size_t)b*2048 + j] = (j < 1024) ? s_t[b*1024+j] : h_t[b*1024+j-1024];
    }
}

// ---------------- K12: vocab softmax in place ----------------
__global__ __launch_bounds__(1024) void vocab_softmax_kernel(
    float* __restrict__ out0, const float* __restrict__ pgen)
{
    __shared__ float rm[1024], rl[1024];
    int b = blockIdx.x, t = threadIdx.x;
    float* row = out0 + (size_t)b*VE_;
    float m = -1e30f, l = 0.f;
    for (int i = t; i < V_; i += 1024) {
        float xv = row[i];
        if (xv > m) { l = l*__expf(m-xv) + 1.f; m = xv; }
        else l += __expf(xv-m);
    }
    rm[t] = m; rl[t] = l; __syncthreads();
    for (int o = 512; o > 0; o >>= 1) {
        if (t < o) {
            float m1 = rm[t], m2 = rm[t+o];
            float M = fmaxf(m1, m2);
            rl[t] = rl[t]*__expf(m1-M) + rl[t+o]*__expf(m2-M);
            rm[t] = M;
        }
        __syncthreads();
    }
    float M = rm[0], inv = pgen[b]/rl[0];
    for (int i = t; i < V_; i += 1024)
        row[i] = __expf(row[i]-M)*inv;
    for (int i = V_ + t; i < VE_; i += 1024)
        row[i] = 0.f;
}

// ---------------- K13: scatter-add copy distribution ----------------
__global__ __launch_bounds__(256) void scatter_kernel(
    const int* __restrict__ ebev, const float* __restrict__ att,
    const float* __restrict__ pgen, float* __restrict__ out0)
{
    int i = blockIdx.x*256 + threadIdx.x;
    int b = i >> 9;
    float val = (1.f - pgen[b]) * att[i];
    int col = ebev[i];
    atomicAdd(out0 + (size_t)b*VE_ + col, val);
}

// ---------------- K14: clip + log in place ----------------
__global__ __launch_bounds__(256) void log_kernel(float* __restrict__ out0)
{
    int i = (blockIdx.x*256 + threadIdx.x) * 4;
    if (i >= B_*VE_) return;
    float4 v = *(float4*)(out0 + i);
    v.x = __logf(fmaxf(v.x, EPS_));
    v.y = __logf(fmaxf(v.y, EPS_));
    v.z = __logf(fmaxf(v.z, EPS_));
    v.w = __logf(fmaxf(v.w, EPS_));
    *(float4*)(out0 + i) = v;
}

extern "C" void kernel_launch(void* const* d_in, const int* in_sizes, int n_in,
                              void* d_out, int out_size, void* d_ws, size_t ws_size,
                              hipStream_t stream) {
    const int*   tok        = (const int*)d_in[0];
    const float* dec_hidden = (const float*)d_in[1];
    const float* enc        = (const float*)d_in[2];
    const float* mask       = (const float*)d_in[3];
    const float* ctx1       = (const float*)d_in[4];
    const int*   ebev       = (const int*)d_in[5];
    const float* cov        = (const float*)d_in[7];
    const float* embed      = (const float*)d_in[8];
    const float* ln_g       = (const float*)d_in[9];
    const float* ln_b       = (const float*)d_in[10];
    const float* xc_W       = (const float*)d_in[11];
    const float* xc_b       = (const float*)d_in[12];
    const float* W_ih       = (const float*)d_in[13];
    const float* W_hh       = (const float*)d_in[14];
    const float* b_ih       = (const float*)d_in[15];
    const float* b_hh       = (const float*)d_in[16];
    const float* Wh         = (const float*)d_in[17];
    const float* Ws         = (const float*)d_in[18];
    const float* Ws_b       = (const float*)d_in[19];
    const float* Wc         = (const float*)d_in[20];
    const float* Vv         = (const float*)d_in[21];
    const float* pg_W       = (const float*)d_in[22];
    const float* pg_b       = (const float*)d_in[23];
    const float* out1_W     = (const float*)d_in[24];
    const float* out1_b     = (const float*)d_in[25];
    const float* out2_W     = (const float*)d_in[26];
    const float* out2_b     = (const float*)d_in[27];

    float* out      = (float*)d_out;
    float* s_t      = out + 6464000;
    float* h_t      = out + 6595072;
    float* cov_next = out + 6726144;
    float* loss     = out + 6791680;

    const size_t ENC_SLOTS = 33554432, WH_SLOTS = 524288;
    const size_t need = (ENC_SLOTS + WH_SLOTS + 5177472) * 4;
    const bool bf16_path = (ws_size >= need);

    float* wsf = (float*)d_ws;
    unsigned short* enc_bf = (unsigned short*)d_ws;
    unsigned short* wh_bf  = (unsigned short*)(wsf + ENC_SLOTS);
    float* base     = bf16_path ? (wsf + ENC_SLOTS + WH_SLOTS) : wsf;
    float* x_cat    = base;             // 262144
    float* x_part   = base + 262144;    // 4 x 131072
    float* x        = base + 786432;    // 131072
    float* gx_part  = base + 917504;    // 2 x 393216
    float* gh_part  = base + 1703936;   // 2 x 393216
    float* ds_part  = base + 2490368;   // 4 x 131072
    float* dec_feat = base + 3014656;   // 131072
    float* e_part   = base + 3145728;   // 8 x 65536
    float* att      = base + 3670016;   // 65536
    float* pgen     = base + 3735552;   // 128
    float* A2       = base + 3735680;   // 262144
    float* h2_part  = base + 3997824;   // 4 x 131072
    float* h2       = base + 4522112;   // 131072
    float* hq       = base + 4653184;   // 4 x 131072

    if (bf16_path) {
        cvt_bf16_kernel<<<32768, 256, 0, stream>>>(enc, enc_bf);
        cvt_bf16_kernel<<<512, 256, 0, stream>>>(Wh, wh_bf);
    }
    embed_ln_kernel<<<128, 256, 0, stream>>>(tok, embed, ln_g, ln_b, ctx1, x_cat);
    gemm128_kernel<<<dim3(16,4), 256, 0, stream>>>(x_cat, xc_W, xc_b, x_part, 1024, 2048, 1024, 512);
    reduce4_kernel<<<512, 256, 0, stream>>>(x_part, x, 131072);
    gemm128_kernel<<<dim3(48,2), 256, 0, stream>>>(x, W_ih, b_ih, gx_part, 3072, 1024, 3072, 512);
    gemm128_kernel<<<dim3(48,2), 256, 0, stream>>>(dec_hidden, W_hh, b_hh, gh_part, 3072, 1024, 3072, 512);
    gru_gate_kernel<<<512, 256, 0, stream>>>(gx_part, gh_part, dec_hidden, s_t);
    gemm128_kernel<<<dim3(16,4), 256, 0, stream>>>(s_t, Ws, Ws_b, ds_part, 1024, 1024, 1024, 256);
    reduce4_kernel<<<512, 256, 0, stream>>>(ds_part, dec_feat, 131072);

    int npart;
    if (bf16_path) {
        attn_gemm_bf16_kernel<<<4096, 256, 0, stream>>>(enc_bf, wh_bf, dec_feat, cov, Wc, Vv, e_part);
        npart = 8;
    } else {
        attn_gemm_f32_kernel<<<2048, 512, 0, stream>>>(enc, Wh, dec_feat, cov, Wc, Vv, e_part);
        npart = 4;
    }
    attn_softmax_kernel<<<128, 256, 0, stream>>>(e_part, npart, mask, cov, att, cov_next, loss);
    dim3 g8(128, 8);
    if (bf16_path)
        context_part_bf16_kernel<<<g8, 256, 0, stream>>>(att, enc_bf, hq);
    else
        context_part_f32_kernel<<<g8, 256, 0, stream>>>(att, enc, hq);
    reduce4_kernel<<<512, 256, 0, stream>>>(hq, h_t, 131072);
    pgen_kernel<<<128, 256, 0, stream>>>(h_t, s_t, x, pg_W, pg_b, pgen, A2);
    gemm128_kernel<<<dim3(16,4), 256, 0, stream>>>(A2, out1_W, out1_b, h2_part, 1024, 2048, 1024, 512);
    reduce4_kernel<<<512, 256, 0, stream>>>(h2_part, h2, 131072);
    gemm128_kernel<<<dim3(782,1), 256, 0, stream>>>(h2, out2_W, out2_b, out, 50000, 1024, VE_, 1024);
    vocab_softmax_kernel<<<128, 1024, 0, stream>>>(out, pgen);
    scatter_kernel<<<256, 256, 0, stream>>>(ebev, att, pgen, out);
    log_kernel<<<6313, 256, 0, stream>>>(out);
}